// Round 2
// baseline (946.037 us; speedup 1.0000x reference)
//
#include <hip/hip_runtime.h>
#include <hip/hip_bf16.h>

// Problem constants (from reference)
#define B_SZ   128
#define S_LEN  512
#define EMB_E  300
#define HID    20
#define NCLS   15

// tanh(z) = 1 - 2/(e^{2z}+1) = 1 - 2/(2^{z*TWO_LOG2E}+1)
#define TWO_LOG2E 2.8853900817779268f

// ---------------------------------------------------------------------------
// Kernel 1: xw[b][s][h] = TWO_LOG2E * (W_ih @ emb[X[b][s]] + b_ih)
// (pre-scaled by 2*log2(e) so the scan's tanh needs only v_exp_f32)
// Grid: 256 blocks x 256 threads, one token per thread.
// t -> (b = t>>9, s = t&511): X reads coalesced; emb row read as 75 float4
// (within-thread sequential -> L1 line reuse); W_ih addresses are wave-uniform
// -> scalar loads (s_load) off the vector-memory path.
// ---------------------------------------------------------------------------
__global__ __launch_bounds__(256) void xw_kernel(
    const int*   __restrict__ X,      // [B][S]
    const float* __restrict__ emb,    // [VOCAB][300]
    const float* __restrict__ W_ih,   // [20][300]
    const float* __restrict__ b_ih,   // [20]
    float*       __restrict__ xw)     // [B][S][20]  (pre-scaled)
{
    const int t = blockIdx.x * blockDim.x + threadIdx.x;   // 0..65535
    const int b = t >> 9;          // 0..127
    const int s = t & 511;         // 0..511

    const int idx = X[b * S_LEN + s];
    const float4* __restrict__ row4 =
        (const float4*)(emb + (long long)idx * EMB_E);

    float acc[HID];
    #pragma unroll
    for (int h = 0; h < HID; ++h) acc[h] = 0.f;

    #pragma unroll 5
    for (int e4 = 0; e4 < EMB_E / 4; ++e4) {       // 75 iterations
        const float4 v = row4[e4];
        #pragma unroll
        for (int h = 0; h < HID; ++h) {
            // wave-uniform address -> scalar load
            const float4 w = *(const float4*)(W_ih + h * EMB_E + e4 * 4);
            acc[h] += v.x * w.x + v.y * w.y + v.z * w.z + v.w * w.w;
        }
    }

    float* __restrict__ o = xw + ((long long)b * S_LEN + s) * HID;
    float r[HID];
    #pragma unroll
    for (int h = 0; h < HID; ++h)
        r[h] = TWO_LOG2E * (acc[h] + b_ih[h]);
    // 20 floats = 5 float4 stores (base is 80B-aligned -> 16B-aligned)
    #pragma unroll
    for (int q = 0; q < HID / 4; ++q)
        ((float4*)o)[q] = ((const float4*)r)[q];
}

// ---------------------------------------------------------------------------
// Cross-lane broadcast at VALU speed: v_readlane_b32 (constant lane index),
// result is an SGPR -> legal single scalar operand of the consuming v_fma.
// ---------------------------------------------------------------------------
__device__ __forceinline__ float bcast(float v, int l) {
    return __builtin_bit_cast(float,
        __builtin_amdgcn_readlane(__builtin_bit_cast(int, v), l));
}

// ---------------------------------------------------------------------------
// Kernel 2: h = tanh-recurrence over 512 steps + linear head.
// One wave per batch element; lane i<20 owns h[i] and (pre-scaled) W_hh row i.
// xw stream is contiguous per block; register prefetch depth 8 hides L2/L3
// latency. Per-step chain: readlane (~8cy) + 5-deep fma tree + v_exp + v_rcp.
// ---------------------------------------------------------------------------
__global__ __launch_bounds__(64) void rnn_scan_kernel(
    const float* __restrict__ xw,     // [B][S][20] pre-scaled by TWO_LOG2E
    const float* __restrict__ h0,     // [B][20]
    const float* __restrict__ W_hh,   // [20][20]
    const float* __restrict__ b_hh,   // [20]
    const float* __restrict__ W_out,  // [15][20]
    const float* __restrict__ b_out,  // [15]
    float*       __restrict__ out)    // [B][15]
{
    const int b    = blockIdx.x;            // 0..127
    const int lane = threadIdx.x;           // 0..63
    const int i    = (lane < HID) ? lane : (HID - 1);   // clamp idle lanes

    // Pre-scaled weights/bias: z_scaled = xv' + bh' + sum_j w'[j]*h[j]
    float w[HID];
    #pragma unroll
    for (int j = 0; j < HID; ++j) w[j] = TWO_LOG2E * W_hh[i * HID + j];
    const float bh = TWO_LOG2E * b_hh[i];

    float h = h0[b * HID + i];

    const float* __restrict__ xb = xw + (long long)b * S_LEN * HID + i;

    // software-pipelined prefetch, depth 8 (static indices only)
    float xbuf[8];
    #pragma unroll
    for (int u = 0; u < 8; ++u) xbuf[u] = xb[u * HID];

    #pragma unroll 1
    for (int s0 = 0; s0 < S_LEN; s0 += 8) {
        #pragma unroll
        for (int u = 0; u < 8; ++u) {
            const float xv = xbuf[u];
            if (s0 + 8 < S_LEN)                       // uniform branch
                xbuf[u] = xb[(s0 + u + 8) * HID];     // prefetch step s+8

            // zs = xv + bh + sum_j w[j]*h_j   (all pre-scaled by 2*log2e)
            float p0 = xv + bh, p1 = 0.f, p2 = 0.f, p3 = 0.f;
            #pragma unroll
            for (int j = 0; j < HID; j += 4) {
                p0 += w[j + 0] * bcast(h, j + 0);
                p1 += w[j + 1] * bcast(h, j + 1);
                p2 += w[j + 2] * bcast(h, j + 2);
                p3 += w[j + 3] * bcast(h, j + 3);
            }
            const float zs = (p0 + p1) + (p2 + p3);

            // tanh: e = 2^zs (= e^{2z}); h = 1 - 2/(e+1)
            float e;
            asm("v_exp_f32 %0, %1" : "=v"(e) : "v"(zs));   // native exp2
            const float r = __builtin_amdgcn_rcpf(e + 1.f);
            h = __builtin_fmaf(-2.f, r, 1.f);
        }
    }

    // Head: out[b][c] = sum_j W_out[c][j] * h[j] + b_out[c]
    const int c = (lane < NCLS) ? lane : 0;
    float wo[HID];
    #pragma unroll
    for (int j = 0; j < HID; ++j) wo[j] = W_out[c * HID + j];

    float a0 = b_out[c], a1 = 0.f, a2 = 0.f, a3 = 0.f;
    #pragma unroll
    for (int j = 0; j < HID; j += 4) {
        a0 += wo[j + 0] * bcast(h, j + 0);
        a1 += wo[j + 1] * bcast(h, j + 1);
        a2 += wo[j + 2] * bcast(h, j + 2);
        a3 += wo[j + 3] * bcast(h, j + 3);
    }
    if (lane < NCLS) out[b * NCLS + c] = (a0 + a1) + (a2 + a3);
}

// ---------------------------------------------------------------------------
extern "C" void kernel_launch(void* const* d_in, const int* in_sizes, int n_in,
                              void* d_out, int out_size, void* d_ws, size_t ws_size,
                              hipStream_t stream) {
    const int*   X     = (const int*)  d_in[0];   // X_batch [128][512]
    const float* h0    = (const float*)d_in[1];   // [128][20]
    const float* emb   = (const float*)d_in[2];   // [500002][300]
    const float* W_ih  = (const float*)d_in[3];   // [20][300]
    const float* b_ih  = (const float*)d_in[4];   // [20]
    const float* W_hh  = (const float*)d_in[5];   // [20][20]
    const float* b_hh  = (const float*)d_in[6];   // [20]
    const float* W_out = (const float*)d_in[7];   // [15][20]
    const float* b_out = (const float*)d_in[8];   // [15]
    float*       out   = (float*)d_out;           // [128][15]

    float* xw = (float*)d_ws;                     // [128][512][20] = 5.24 MB

    xw_kernel<<<256, 256, 0, stream>>>(X, emb, W_ih, b_ih, xw);
    rnn_scan_kernel<<<B_SZ, 64, 0, stream>>>(xw, h0, W_hh, b_hh,
                                             W_out, b_out, out);
}

// Round 3
// 864.656 us; speedup vs baseline: 1.0941x; 1.0941x over previous
//
#include <hip/hip_runtime.h>
#include <hip/hip_bf16.h>

// Problem constants (from reference)
#define B_SZ   128
#define S_LEN  512
#define EMB_E  300
#define HID    20
#define NCLS   15

// tanh(z) = 1 - 2/(e^{2z}+1) = 1 - 2/(2^{z*TWO_LOG2E}+1)
#define TWO_LOG2E 2.8853900817779268f

// Cross-lane broadcast at VALU speed: v_readlane_b32 (constant lane index),
// result is an SGPR -> legal single scalar operand of the consuming v_fma.
__device__ __forceinline__ float bcast(float v, int l) {
    return __builtin_bit_cast(float,
        __builtin_amdgcn_readlane(__builtin_bit_cast(int, v), l));
}

// ---------------------------------------------------------------------------
// Fused kernel: one block per batch element b.
//  Phase 1 (512 threads): xw[s][h] = 2log2e*(W_ih @ emb[X[b][s]] + b_ih) -> LDS
//    - thread t projects token s=t: 75 coalesced float4 reads of its emb row
//      (each 64B line used fully across the e4 loop), W_ih reads wave-uniform
//      -> scalar pipe. xw never touches HBM (was a 5.24MB ws round-trip with
//      cross-XCD L2-miss exposure; now 40KB LDS, fixed ~120cy latency).
//  Phase 2 (wave 0 only): 512-step tanh recurrence + linear head.
//    - lane i<20 owns h[i] and pre-scaled W_hh row i; h broadcast via
//      v_readlane (const lane); 4-way split FMA tree; tanh via one v_exp_f32
//      (inputs pre-scaled by 2*log2e) + v_rcp; depth-4 LDS prefetch.
//    - arithmetic order identical to the round-2 version (absmax 0.0).
// ---------------------------------------------------------------------------
__global__ __launch_bounds__(512) void rnn_fused_kernel(
    const int*   __restrict__ X,      // [B][S]
    const float* __restrict__ emb,    // [VOCAB][300]
    const float* __restrict__ W_ih,   // [20][300]
    const float* __restrict__ b_ih,   // [20]
    const float* __restrict__ h0,     // [B][20]
    const float* __restrict__ W_hh,   // [20][20]
    const float* __restrict__ b_hh,   // [20]
    const float* __restrict__ W_out,  // [15][20]
    const float* __restrict__ b_out,  // [15]
    float*       __restrict__ out)    // [B][15]
{
    __shared__ float xw[S_LEN * HID];          // 40 KB

    const int b = blockIdx.x;                  // 0..127
    const int t = threadIdx.x;                 // 0..511

    // ---------------- Phase 1: input projection into LDS ----------------
    {
        const int s   = t;                     // one token per thread
        const int idx = X[b * S_LEN + s];
        const float4* __restrict__ row4 =
            (const float4*)(emb + (long long)idx * EMB_E);

        float acc[HID];
        #pragma unroll
        for (int h = 0; h < HID; ++h) acc[h] = 0.f;

        #pragma unroll 5
        for (int e4 = 0; e4 < EMB_E / 4; ++e4) {       // 75 iterations
            const float4 v = row4[e4];
            #pragma unroll
            for (int h = 0; h < HID; ++h) {
                // wave-uniform address -> scalar load
                const float4 w = *(const float4*)(W_ih + h * EMB_E + e4 * 4);
                acc[h] += v.x * w.x + v.y * w.y + v.z * w.z + v.w * w.w;
            }
        }

        float r[HID];
        #pragma unroll
        for (int h = 0; h < HID; ++h)
            r[h] = TWO_LOG2E * (acc[h] + b_ih[h]);
        float4* __restrict__ o = (float4*)(xw + s * HID);  // 80B base -> 16B ok
        #pragma unroll
        for (int q = 0; q < HID / 4; ++q)
            o[q] = ((const float4*)r)[q];
    }
    __syncthreads();

    // ---------------- Phase 2: sequential scan (wave 0 only) ----------------
    if (t >= 64) return;                       // no further barriers -> legal
    const int lane = t;
    const int i    = (lane < HID) ? lane : (HID - 1);   // clamp idle lanes

    float w[HID];
    #pragma unroll
    for (int j = 0; j < HID; ++j) w[j] = TWO_LOG2E * W_hh[i * HID + j];
    const float bh = TWO_LOG2E * b_hh[i];

    float h = h0[b * HID + i];

    const float* __restrict__ xb = xw + i;     // LDS stream, stride 80B

    float xbuf[4];                             // depth-4 prefetch, static idx
    #pragma unroll
    for (int u = 0; u < 4; ++u) xbuf[u] = xb[u * HID];

    #pragma unroll 1
    for (int s0 = 0; s0 < S_LEN; s0 += 4) {
        #pragma unroll
        for (int u = 0; u < 4; ++u) {
            const float xv = xbuf[u];
            if (s0 + 4 < S_LEN)                        // uniform branch
                xbuf[u] = xb[(s0 + u + 4) * HID];      // prefetch step s+4

            // zs = xv + bh + sum_j w[j]*h_j   (all pre-scaled by 2*log2e)
            float p0 = xv + bh, p1 = 0.f, p2 = 0.f, p3 = 0.f;
            #pragma unroll
            for (int j = 0; j < HID; j += 4) {
                p0 += w[j + 0] * bcast(h, j + 0);
                p1 += w[j + 1] * bcast(h, j + 1);
                p2 += w[j + 2] * bcast(h, j + 2);
                p3 += w[j + 3] * bcast(h, j + 3);
            }
            const float zs = (p0 + p1) + (p2 + p3);

            // tanh: e = 2^zs (= e^{2z}); h = 1 - 2/(e+1)
            float e;
            asm("v_exp_f32 %0, %1" : "=v"(e) : "v"(zs));   // native exp2
            const float r = __builtin_amdgcn_rcpf(e + 1.f);
            h = __builtin_fmaf(-2.f, r, 1.f);
        }
    }

    // ---------------- Head: out[b][c] = W_out @ h + b_out ----------------
    const int c = (lane < NCLS) ? lane : 0;
    float wo[HID];
    #pragma unroll
    for (int j = 0; j < HID; ++j) wo[j] = W_out[c * HID + j];

    float a0 = b_out[c], a1 = 0.f, a2 = 0.f, a3 = 0.f;
    #pragma unroll
    for (int j = 0; j < HID; j += 4) {
        a0 += wo[j + 0] * bcast(h, j + 0);
        a1 += wo[j + 1] * bcast(h, j + 1);
        a2 += wo[j + 2] * bcast(h, j + 2);
        a3 += wo[j + 3] * bcast(h, j + 3);
    }
    if (lane < NCLS) out[b * NCLS + c] = (a0 + a1) + (a2 + a3);
}

// ---------------------------------------------------------------------------
extern "C" void kernel_launch(void* const* d_in, const int* in_sizes, int n_in,
                              void* d_out, int out_size, void* d_ws, size_t ws_size,
                              hipStream_t stream) {
    const int*   X     = (const int*)  d_in[0];   // X_batch [128][512]
    const float* h0    = (const float*)d_in[1];   // [128][20]
    const float* emb   = (const float*)d_in[2];   // [500002][300]
    const float* W_ih  = (const float*)d_in[3];   // [20][300]
    const float* b_ih  = (const float*)d_in[4];   // [20]
    const float* W_hh  = (const float*)d_in[5];   // [20][20]
    const float* b_hh  = (const float*)d_in[6];   // [20]
    const float* W_out = (const float*)d_in[7];   // [15][20]
    const float* b_out = (const float*)d_in[8];   // [15]
    float*       out   = (float*)d_out;           // [128][15]

    rnn_fused_kernel<<<B_SZ, 512, 0, stream>>>(X, emb, W_ih, b_ih, h0,
                                               W_hh, b_hh, W_out, b_out, out);
}